// Round 1
// 1008.790 us; speedup vs baseline: 1.0442x; 1.0442x over previous
//
#include <hip/hip_runtime.h>
#include <math.h>

// Problem constants (from reference):
//   x: [4096, 49152] f32, weight: [16384, 6] f32, out: [4096, 3] f32
static constexpr int NB   = 16384;        // number of 3x3 blocks
static constexpr int COLS = NB * 3;       // 49152
static constexpr int VEC  = COLS / 4;     // 12288 float4 per row
static constexpr int ROWS = 4096;
static constexpr int TPB  = 256;

// Column chunking: W slice held in REGISTERS per block (no global re-reads).
static constexpr int CHUNKS    = 12;               // 4096 cols per chunk
static constexpr int CHUNK_VEC = VEC / CHUNKS;     // 1024 float4
static constexpr int SLOTS     = CHUNK_VEC / TPB;  // 4 float4 per thread per stream
static constexpr int ROW_TILE  = 32;               // rows amortizing the W regs
static constexpr int ROW_TILES = ROWS / ROW_TILE;  // 128
static constexpr int WAVES     = TPB / 64;         // 4
static constexpr int NPART     = CHUNKS * WAVES;   // 48 partials per row

__device__ __forceinline__ float softplus_f(float v) {
    return log1pf(expf(-fabsf(v))) + fmaxf(v, 0.0f);
}

// Expand weight [NB,6] -> three SoA arrays Wj[COLS], Wj[3n+i] = W[n][j][i]
__global__ void build_wexp(const float* __restrict__ w,
                           float* __restrict__ W0,
                           float* __restrict__ W1,
                           float* __restrict__ W2) {
    int n = blockIdx.x * blockDim.x + threadIdx.x;
    if (n >= NB) return;
    float w0 = w[n * 6 + 0], w1 = w[n * 6 + 1], w2 = w[n * 6 + 2];
    float w3 = w[n * 6 + 3], w4 = w[n * 6 + 4], w5 = w[n * 6 + 5];
    float a = softplus_f(w0), b = w1, c = w2;
    float d = softplus_f(w3), e = w4, f = softplus_f(w5);
    float W00 = a * a;
    float W01 = a * b;
    float W02 = a * c;
    float W11 = b * b + d * d;
    float W12 = b * c + d * e;
    float W22 = c * c + e * e + f * f;
    int base = 3 * n;
    W0[base + 0] = W00; W0[base + 1] = W01; W0[base + 2] = W02;
    W1[base + 0] = W01; W1[base + 1] = W11; W1[base + 2] = W12;
    W2[base + 0] = W02; W2[base + 1] = W12; W2[base + 2] = W22;
}

// Each block: one (chunk, row-tile) pair. W slice lives in registers
// (loaded once, reused for ROW_TILE rows) -> W global traffic drops from
// 2.36 GB (once per row) to <=74 MB (once per block, mostly L2-hit).
// x is read exactly once, fully coalesced float4.
__global__ __launch_bounds__(TPB) void partial_gemv(
    const float4* __restrict__ x,
    const float4* __restrict__ W0,
    const float4* __restrict__ W1,
    const float4* __restrict__ W2,
    float* __restrict__ partial) {
    const int chunk = blockIdx.x % CHUNKS;
    const int rt    = blockIdx.x / CHUNKS;
    const int t     = threadIdx.x;
    const int vbase = chunk * CHUNK_VEC;

    // W slice -> registers: SLOTS x 3 float4 = 48 VGPRs
    float4 q0[SLOTS], q1[SLOTS], q2[SLOTS];
    #pragma unroll
    for (int s = 0; s < SLOTS; ++s) {
        const int v = vbase + t + s * TPB;
        q0[s] = W0[v];
        q1[s] = W1[v];
        q2[s] = W2[v];
    }

    const int r0   = rt * ROW_TILE;
    const int lane = t & 63;
    const int wv   = t >> 6;

    for (int r = 0; r < ROW_TILE; ++r) {
        const float4* __restrict__ xr =
            x + (size_t)(r0 + r) * VEC + vbase;

        // batch the 4 x-loads so they are all in flight before the FMAs
        float4 xv[SLOTS];
        #pragma unroll
        for (int s = 0; s < SLOTS; ++s) xv[s] = xr[t + s * TPB];

        float a0 = 0.f, a1 = 0.f, a2 = 0.f;
        #pragma unroll
        for (int s = 0; s < SLOTS; ++s) {
            a0 = fmaf(xv[s].x, q0[s].x,
                 fmaf(xv[s].y, q0[s].y,
                 fmaf(xv[s].z, q0[s].z,
                 fmaf(xv[s].w, q0[s].w, a0))));
            a1 = fmaf(xv[s].x, q1[s].x,
                 fmaf(xv[s].y, q1[s].y,
                 fmaf(xv[s].z, q1[s].z,
                 fmaf(xv[s].w, q1[s].w, a1))));
            a2 = fmaf(xv[s].x, q2[s].x,
                 fmaf(xv[s].y, q2[s].y,
                 fmaf(xv[s].z, q2[s].z,
                 fmaf(xv[s].w, q2[s].w, a2))));
        }

        // wave-64 butterfly reduce; no cross-wave sync needed (per-wave partials)
        #pragma unroll
        for (int off = 32; off > 0; off >>= 1) {
            a0 += __shfl_down(a0, off);
            a1 += __shfl_down(a1, off);
            a2 += __shfl_down(a2, off);
        }

        if (lane == 0) {
            float* p = partial +
                ((size_t)(r0 + r) * NPART + chunk * WAVES + wv) * 3;
            p[0] = a0;
            p[1] = a1;
            p[2] = a2;
        }
    }
}

// out[row][j] = sum over 48 partials; deterministic fixed-order sum.
__global__ __launch_bounds__(TPB) void reduce_partials(
    const float* __restrict__ partial, float* __restrict__ out) {
    const int tid = blockIdx.x * blockDim.x + threadIdx.x;
    if (tid >= ROWS * 3) return;
    const int row = tid / 3;
    const int j   = tid % 3;
    const float* p = partial + (size_t)row * NPART * 3 + j;
    float s = 0.f;
    #pragma unroll
    for (int i = 0; i < NPART; ++i) s += p[i * 3];
    out[tid] = s;
}

extern "C" void kernel_launch(void* const* d_in, const int* in_sizes, int n_in,
                              void* d_out, int out_size, void* d_ws, size_t ws_size,
                              hipStream_t stream) {
    const float* x = (const float*)d_in[0];
    const float* w = (const float*)d_in[1];
    float* out = (float*)d_out;

    // workspace: 3*COLS floats expanded W (576 KB) + ROWS*NPART*3 partials (2.25 MB)
    float* W0 = (float*)d_ws;
    float* W1 = W0 + COLS;
    float* W2 = W1 + COLS;
    float* partial = W2 + COLS;

    build_wexp<<<(NB + TPB - 1) / TPB, TPB, 0, stream>>>(w, W0, W1, W2);
    partial_gemv<<<CHUNKS * ROW_TILES, TPB, 0, stream>>>(
        (const float4*)x, (const float4*)W0, (const float4*)W1,
        (const float4*)W2, partial);
    reduce_partials<<<(ROWS * 3 + TPB - 1) / TPB, TPB, 0, stream>>>(partial, out);
}